// Round 14
// baseline (785.475 us; speedup 1.0000x reference)
//
#include <hip/hip_runtime.h>
#include <hip/hip_bf16.h>
#include <cstdint>

#define DEV static __device__ __forceinline__

typedef __attribute__((ext_vector_type(8))) __bf16 bf16x8;
typedef __attribute__((ext_vector_type(4))) float f32x4;
typedef __attribute__((ext_vector_type(8))) unsigned short ushort8;
typedef __attribute__((ext_vector_type(4))) unsigned int uint4v;

constexpr int NTOK = 65536;
constexpr int E = 1024;

DEV unsigned short f2b(float f) {
  unsigned int u = __builtin_bit_cast(unsigned int, f);
  u += 0x7fffu + ((u >> 16) & 1u);
  return (unsigned short)(u >> 16);
}

DEV f32x4 mfma16(bf16x8 a, bf16x8 b, f32x4 c) {
  return __builtin_amdgcn_mfma_f32_16x16x32_bf16(a, b, c, 0, 0, 0);
}

DEV void gload16(const void* g, const void* l) {
  __builtin_amdgcn_global_load_lds(
      (const __attribute__((address_space(1))) void*)g,
      (__attribute__((address_space(3))) void*)l, 16, 0, 0);
}

DEV void BAR() {
  asm volatile("" ::: "memory");
  __builtin_amdgcn_s_barrier();
  asm volatile("" ::: "memory");
  __builtin_amdgcn_sched_barrier(0);
}

#define WAITVM(n_) do { \
  asm volatile("s_waitcnt vmcnt(" #n_ ")" ::: "memory"); \
  __builtin_amdgcn_sched_barrier(0); \
} while (0)

// ---------------- fp32 -> bf16 convert, single launch for x + all weights ----
__global__ void cvtAll(const float* __restrict__ x, const float* __restrict__ Wq,
                       const float* __restrict__ Wk, const float* __restrict__ Wv,
                       const float* __restrict__ Wo,
                       unsigned short* __restrict__ xb,
                       unsigned short* __restrict__ wout) {
  int b = blockIdx.x;
  const float* src;
  unsigned short* dst;
  size_t j;
  if (b < 32768) {
    src = x;
    dst = xb;
    j = (size_t)b * 256 + threadIdx.x;
  } else {
    int i = (b - 32768) * 256 + threadIdx.x;  // 0..524287
    int wsel = i >> 17;
    src = wsel == 0 ? Wq : wsel == 1 ? Wk : wsel == 2 ? Wv : Wo;
    dst = wout + ((size_t)wsel << 20);
    j = (size_t)(i & 131071);
  }
  const float4* p = (const float4*)(src + j * 8);
  float4 a = p[0], c = p[1];
  ushort8 r;
  r[0] = f2b(a.x); r[1] = f2b(a.y); r[2] = f2b(a.z); r[3] = f2b(a.w);
  r[4] = f2b(c.x); r[5] = f2b(c.y); r[6] = f2b(c.z); r[7] = f2b(c.w);
  *(ushort8*)(dst + j * 8) = r;
}

// ---------------------------------------------------------------------------
// R3-PROVEN GEMM: 256x256-tile, BK=64, 8-wave (2Mx4N), 8 phases / 2 K-tiles,
// compile-time LDS offsets. T1 XCD swizzle, T2 st-swizzle, T3/T4 counted
// vmcnt(6), T5 setprio. LDS 128 KiB. K % 128 == 0.
// NEW: C stored with __builtin_nontemporal_store (streamed output never
// re-read before full overwrite; keeps B weight panels L2/L3-resident).
// ---------------------------------------------------------------------------
template <typename OutT>
__global__ __launch_bounds__(512, 2) void gemm8(
    const unsigned short* __restrict__ A, const unsigned short* __restrict__ B,
    OutT* __restrict__ C, int M, int N, int K, int nbx) {
  __shared__ char smem[131072];
  char* sA = smem;
  char* sB = smem + 65536;

  const int NT = K >> 6;
  const int nwg = gridDim.x;
  const int cpx = nwg >> 3;
  const int wg = ((int)blockIdx.x & 7) * cpx + ((int)blockIdx.x >> 3);
  const int tm = (wg / nbx) * 256;
  const int tn = (wg % nbx) * 256;

  const int t = threadIdx.x;
  const int w = t >> 6, l = t & 63;
  const int wr = w >> 2, wc = w & 3;  // 2 x 4 wave grid
  const int lr = l & 15, q = l >> 4;

  const int srow = w * 8 + (l >> 3);
  const int scol = ((l & 7) ^ (l >> 3)) * 8;
  const int xorv = (lr & 7) << 4;
  const int offk0 = (q * 16) ^ xorv;
  const int offk1 = (64 + q * 16) ^ xorv;
  const int aRB = wr * 8192 + lr * 128;
  const int bRB = wc * 4096 + lr * 128;

#define STAGE_A(tt_, h_) do { \
    const unsigned short* g_ = A + (size_t)(tm + (h_)*128 + srow) * K + (tt_)*64 + scol; \
    const char* d_ = sA + (((tt_) & 1) * 32768 + (h_)*16384 + w * 1024); \
    gload16(g_, d_); \
    gload16(g_ + (size_t)64 * K, d_ + 8192); \
  } while (0)

#define STAGE_B(tt_, h_) do { \
    const unsigned short* g_ = B + (size_t)(tn + (h_)*128 + srow) * K + (tt_)*64 + scol; \
    const char* d_ = sB + (((tt_) & 1) * 32768 + (h_)*16384 + w * 1024); \
    gload16(g_, d_); \
    gload16(g_ + (size_t)64 * K, d_ + 8192); \
  } while (0)

  f32x4 acc[8][4] = {};
  bf16x8 af[4][2];
  bf16x8 bf_[2][2][2];

#define LDA(buf_, mh_) do { \
    _Pragma("unroll") for (int m_ = 0; m_ < 4; ++m_) { \
      af[m_][0] = *(const bf16x8*)(sA + (buf_)*32768 + (mh_)*16384 + m_*2048 + aRB + offk0); \
      af[m_][1] = *(const bf16x8*)(sA + (buf_)*32768 + (mh_)*16384 + m_*2048 + aRB + offk1); \
    } \
  } while (0)

#define LDB(buf_, nh_) do { \
    _Pragma("unroll") for (int n_ = 0; n_ < 2; ++n_) { \
      bf_[nh_][n_][0] = *(const bf16x8*)(sB + (buf_)*32768 + (nh_)*16384 + n_*2048 + bRB + offk0); \
      bf_[nh_][n_][1] = *(const bf16x8*)(sB + (buf_)*32768 + (nh_)*16384 + n_*2048 + bRB + offk1); \
    } \
  } while (0)

#define MM(mh_, nh_) do { \
    __builtin_amdgcn_s_setprio(1); \
    _Pragma("unroll") for (int m_ = 0; m_ < 4; ++m_) \
      _Pragma("unroll") for (int n_ = 0; n_ < 2; ++n_) { \
        acc[(mh_)*4 + m_][(nh_)*2 + n_] = \
            mfma16(af[m_][0], bf_[nh_][n_][0], acc[(mh_)*4 + m_][(nh_)*2 + n_]); \
        acc[(mh_)*4 + m_][(nh_)*2 + n_] = \
            mfma16(af[m_][1], bf_[nh_][n_][1], acc[(mh_)*4 + m_][(nh_)*2 + n_]); \
      } \
    __builtin_amdgcn_s_setprio(0); \
  } while (0)

  // ---- prologue: tile0 fully, tile1 first 3 half-tiles; drain tile0 ----
  STAGE_A(0, 0); STAGE_B(0, 0); STAGE_B(0, 1); STAGE_A(0, 1);
  STAGE_A(1, 0); STAGE_B(1, 0); STAGE_B(1, 1);
  WAITVM(6);
  BAR();

  int T = 0;
  for (; T + 3 < NT; T += 2) {
    LDA(0, 0); LDB(0, 0);
    STAGE_A(T + 1, 1);
    BAR(); MM(0, 0); BAR();
    LDB(0, 1);
    STAGE_A(T + 2, 0);
    BAR(); MM(0, 1); BAR();
    LDA(0, 1);
    STAGE_B(T + 2, 0);
    BAR(); MM(1, 0); BAR();
    STAGE_B(T + 2, 1);
    WAITVM(6);
    BAR(); MM(1, 1); BAR();
    LDA(1, 0); LDB(1, 0);
    STAGE_A(T + 2, 1);
    BAR(); MM(0, 0); BAR();
    LDB(1, 1);
    STAGE_A(T + 3, 0);
    BAR(); MM(0, 1); BAR();
    LDA(1, 1);
    STAGE_B(T + 3, 0);
    BAR(); MM(1, 0); BAR();
    STAGE_B(T + 3, 1);
    WAITVM(6);
    BAR(); MM(1, 1); BAR();
  }
  {
    LDA(0, 0); LDB(0, 0);
    STAGE_A(T + 1, 1);
    BAR(); MM(0, 0); BAR();
    LDB(0, 1);
    BAR(); MM(0, 1); BAR();
    LDA(0, 1);
    BAR(); MM(1, 0); BAR();
    WAITVM(0);
    BAR(); MM(1, 1); BAR();
    LDA(1, 0); LDB(1, 0);
    BAR(); MM(0, 0); BAR();
    LDB(1, 1);
    BAR(); MM(0, 1); BAR();
    LDA(1, 1);
    BAR(); MM(1, 0); BAR();
    BAR(); MM(1, 1); BAR();
  }

#pragma unroll
  for (int mh = 0; mh < 2; ++mh)
#pragma unroll
    for (int m = 0; m < 4; ++m)
#pragma unroll
      for (int nh = 0; nh < 2; ++nh)
#pragma unroll
        for (int n = 0; n < 2; ++n)
#pragma unroll
          for (int j = 0; j < 4; ++j) {
            int row = tm + mh * 128 + wr * 64 + m * 16 + q * 4 + j;
            int col = tn + nh * 128 + wc * 32 + n * 16 + lr;
            float v = acc[mh * 4 + m][nh * 2 + n][j];
            if constexpr (sizeof(OutT) == 2)
              __builtin_nontemporal_store((OutT)f2b(v), &C[(size_t)row * N + col]);
            else
              __builtin_nontemporal_store(v, &C[(size_t)row * N + col]);
          }
#undef STAGE_A
#undef STAGE_B
#undef LDA
#undef LDB
#undef MM
}

// ---------------- per-token 16-head attention over head axis ----------------
// R12-proven: swapped QK^T, in-register softmax, shuffle-gathered PV
// A-fragment, distributed all-lane V fetch + shfl_xor(32) reassembly, no LDS.
// att output stays CACHEABLE (re-read immediately by O-proj; 128 MB fits L3).
__global__ __launch_bounds__(256, 4) void attn16(
    const unsigned short* __restrict__ qkv, unsigned short* __restrict__ out) {
  const int t = threadIdx.x, w = t >> 6, l = t & 63;
  const int tok = blockIdx.x * 4 + w;
  const unsigned short* q = qkv + (size_t)tok * 3072;
  const unsigned short* kp = q + 1024;
  const unsigned short* vp = q + 2048;
  const int lr = l & 15, lk = (l >> 4) * 8;

  bf16x8 aq0 = *reinterpret_cast<const bf16x8*>(q + lr * 64 + lk);
  bf16x8 aq1 = *reinterpret_cast<const bf16x8*>(q + lr * 64 + 32 + lk);
  bf16x8 bk0 = *reinterpret_cast<const bf16x8*>(kp + lr * 64 + lk);
  bf16x8 bk1 = *reinterpret_cast<const bf16x8*>(kp + lr * 64 + 32 + lk);

  const int myLk = ((l >> 4) & 1) * 8;  // shared by l and l^32
  const int jb = (l >> 5) * 4;          // 0 lower half, 4 upper half
  unsigned vlo[4], vhi[4];
#pragma unroll
  for (int b = 0; b < 4; ++b) {
    const unsigned short* vb = vp + (size_t)(myLk + jb) * 64 + b * 16 + lr;
    unsigned short e0 = vb[0];
    unsigned short e1 = vb[64];
    unsigned short e2 = vb[128];
    unsigned short e3 = vb[192];
    vlo[b] = (unsigned)e0 | ((unsigned)e1 << 16);
    vhi[b] = (unsigned)e2 | ((unsigned)e3 << 16);
  }

  f32x4 s = {};
  __builtin_amdgcn_s_setprio(1);
  s = mfma16(bk0, aq0, s);  // swapped: S^T
  s = mfma16(bk1, aq1, s);
  __builtin_amdgcn_s_setprio(0);

  const float cexp = 0.125f * 1.44269504f;
  float mx = fmaxf(fmaxf(s[0], s[1]), fmaxf(s[2], s[3]));
  mx = fmaxf(mx, __shfl_xor(mx, 16));
  mx = fmaxf(mx, __shfl_xor(mx, 32));
  float e0 = exp2f((s[0] - mx) * cexp);
  float e1 = exp2f((s[1] - mx) * cexp);
  float e2 = exp2f((s[2] - mx) * cexp);
  float e3 = exp2f((s[3] - mx) * cexp);
  float sm = (e0 + e1) + (e2 + e3);
  sm += __shfl_xor(sm, 16);
  sm += __shfl_xor(sm, 32);
  float inv = 1.0f / sm;
  float p[4] = {e0 * inv, e1 * inv, e2 * inv, e3 * inv};

  ushort8 au;
#pragma unroll
  for (int jj = 0; jj < 8; ++jj) {
    int src = (lr + (l >> 4) * 32 + (jj >> 2) * 16) & 63;
    float v = __shfl(p[jj & 3], src);
    au[jj] = (l < 32) ? f2b(v) : (unsigned short)0;
  }
  bf16x8 ap = __builtin_bit_cast(bf16x8, au);

  bf16x8 bv[4];
#pragma unroll
  for (int b = 0; b < 4; ++b) {
    unsigned plo = (unsigned)__shfl_xor((int)vlo[b], 32);
    unsigned phi = (unsigned)__shfl_xor((int)vhi[b], 32);
    uint4v u = {vlo[b], vhi[b], plo, phi};
    bv[b] = __builtin_bit_cast(bf16x8, u);
  }

  f32x4 o[4] = {};
  __builtin_amdgcn_s_setprio(1);
#pragma unroll
  for (int b = 0; b < 4; ++b) o[b] = mfma16(ap, bv[b], o[b]);
  __builtin_amdgcn_s_setprio(0);

  unsigned short* op = out + (size_t)tok * 1024;
#pragma unroll
  for (int b = 0; b < 4; ++b)
#pragma unroll
    for (int j = 0; j < 4; ++j)
      op[((l >> 4) * 4 + j) * 64 + b * 16 + lr] = f2b(o[b][j]);
}

// ---------------------------------------------------------------------------
extern "C" void kernel_launch(void* const* d_in, const int* in_sizes, int n_in,
                              void* d_out, int out_size, void* d_ws, size_t ws_size,
                              hipStream_t stream) {
  const float* x = (const float*)d_in[0];
  const float* Wq = (const float*)d_in[1];
  const float* Wk = (const float*)d_in[2];
  const float* Wv = (const float*)d_in[3];
  const float* Wo = (const float*)d_in[4];

  unsigned short* xb = (unsigned short*)d_ws;            // 64M elems (128 MB)
  unsigned short* wqkv = xb + (size_t)NTOK * E;          // 3M (6 MB)
  unsigned short* wo = wqkv + (size_t)3 * E * E;         // 1M (2 MB)
  unsigned short* qkv = wo + (size_t)E * E;              // 192M (384 MB)
  unsigned short* att = qkv + (size_t)NTOK * 3 * E;      // 64M (128 MB)

  // single convert launch: x (blocks 0..32767) + Wq|Wk|Wv|Wo (32768..34815)
  cvtAll<<<34816, 256, 0, stream>>>(x, Wq, Wk, Wv, Wo, xb, wqkv);

  // QKV: [65536,1024] x [3072,1024]^T -> [65536,3072]
  gemm8<unsigned short><<<(NTOK / 256) * (3 * E / 256), 512, 0, stream>>>(
      xb, wqkv, qkv, NTOK, 3 * E, E, 3 * E / 256);

  attn16<<<NTOK / 4, 256, 0, stream>>>(qkv, att);

  // O-proj: [65536,1024] x [1024,1024]^T -> fp32
  gemm8<float><<<(NTOK / 256) * (E / 256), 512, 0, stream>>>(
      att, wo, (float*)d_out, NTOK, E, E, E / 256);
}

// Round 15
// 727.353 us; speedup vs baseline: 1.0799x; 1.0799x over previous
//
#include <hip/hip_runtime.h>
#include <hip/hip_bf16.h>
#include <cstdint>

#define DEV static __device__ __forceinline__

typedef __attribute__((ext_vector_type(8))) __bf16 bf16x8;
typedef __attribute__((ext_vector_type(4))) float f32x4;
typedef __attribute__((ext_vector_type(8))) unsigned short ushort8;
typedef __attribute__((ext_vector_type(4))) unsigned int uint4v;

constexpr int NTOK = 65536;
constexpr int E = 1024;

DEV unsigned short f2b(float f) {
  unsigned int u = __builtin_bit_cast(unsigned int, f);
  u += 0x7fffu + ((u >> 16) & 1u);
  return (unsigned short)(u >> 16);
}

DEV f32x4 mfma16(bf16x8 a, bf16x8 b, f32x4 c) {
  return __builtin_amdgcn_mfma_f32_16x16x32_bf16(a, b, c, 0, 0, 0);
}

DEV void gload16(const void* g, const void* l) {
  __builtin_amdgcn_global_load_lds(
      (const __attribute__((address_space(1))) void*)g,
      (__attribute__((address_space(3))) void*)l, 16, 0, 0);
}

DEV void BAR() {
  asm volatile("" ::: "memory");
  __builtin_amdgcn_s_barrier();
  asm volatile("" ::: "memory");
  __builtin_amdgcn_sched_barrier(0);
}

#define WAITVM(n_) do { \
  asm volatile("s_waitcnt vmcnt(" #n_ ")" ::: "memory"); \
  __builtin_amdgcn_sched_barrier(0); \
} while (0)

// ---------------- fp32 -> bf16 convert, single launch for x + all weights ----
// blocks [0, 32768): x (64M elems); blocks [32768, 34816): Wq|Wk|Wv|Wo.
__global__ void cvtAll(const float* __restrict__ x, const float* __restrict__ Wq,
                       const float* __restrict__ Wk, const float* __restrict__ Wv,
                       const float* __restrict__ Wo,
                       unsigned short* __restrict__ xb,
                       unsigned short* __restrict__ wout) {
  int b = blockIdx.x;
  const float* src;
  unsigned short* dst;
  size_t j;
  if (b < 32768) {
    src = x;
    dst = xb;
    j = (size_t)b * 256 + threadIdx.x;
  } else {
    int i = (b - 32768) * 256 + threadIdx.x;  // 0..524287
    int wsel = i >> 17;
    src = wsel == 0 ? Wq : wsel == 1 ? Wk : wsel == 2 ? Wv : Wo;
    dst = wout + ((size_t)wsel << 20);
    j = (size_t)(i & 131071);
  }
  const float4* p = (const float4*)(src + j * 8);
  float4 a = p[0], c = p[1];
  ushort8 r;
  r[0] = f2b(a.x); r[1] = f2b(a.y); r[2] = f2b(a.z); r[3] = f2b(a.w);
  r[4] = f2b(c.x); r[5] = f2b(c.y); r[6] = f2b(c.z); r[7] = f2b(c.w);
  *(ushort8*)(dst + j * 8) = r;
}

// ---------------------------------------------------------------------------
// R3-PROVEN GEMM (verbatim): 256x256-tile, BK=64, 8-wave (2Mx4N), 8 phases /
// 2 K-tiles with compile-time LDS offsets. T1 XCD swizzle, T2 st-swizzle
// (pre-swizzled global source + XOR'd ds_read), T3/T4 counted vmcnt(6),
// T5 setprio. LDS 128 KiB. Requires K % 128 == 0.
// Empirical ceiling for this shape (NT=16): 5 variants falsified against it
// (persistent, 32x32 MFMA, 2-block-occupancy tile, merged 2-phase, nt-stores).
// ---------------------------------------------------------------------------
template <typename OutT>
__global__ __launch_bounds__(512, 2) void gemm8(
    const unsigned short* __restrict__ A, const unsigned short* __restrict__ B,
    OutT* __restrict__ C, int M, int N, int K, int nbx) {
  __shared__ char smem[131072];
  char* sA = smem;
  char* sB = smem + 65536;

  const int NT = K >> 6;
  const int nwg = gridDim.x;
  const int cpx = nwg >> 3;
  const int wg = ((int)blockIdx.x & 7) * cpx + ((int)blockIdx.x >> 3);
  const int tm = (wg / nbx) * 256;
  const int tn = (wg % nbx) * 256;

  const int t = threadIdx.x;
  const int w = t >> 6, l = t & 63;
  const int wr = w >> 2, wc = w & 3;  // 2 x 4 wave grid
  const int lr = l & 15, q = l >> 4;

  const int srow = w * 8 + (l >> 3);
  const int scol = ((l & 7) ^ (l >> 3)) * 8;
  const int xorv = (lr & 7) << 4;
  const int offk0 = (q * 16) ^ xorv;
  const int offk1 = (64 + q * 16) ^ xorv;
  const int aRB = wr * 8192 + lr * 128;
  const int bRB = wc * 4096 + lr * 128;

#define STAGE_A(tt_, h_) do { \
    const unsigned short* g_ = A + (size_t)(tm + (h_)*128 + srow) * K + (tt_)*64 + scol; \
    const char* d_ = sA + (((tt_) & 1) * 32768 + (h_)*16384 + w * 1024); \
    gload16(g_, d_); \
    gload16(g_ + (size_t)64 * K, d_ + 8192); \
  } while (0)

#define STAGE_B(tt_, h_) do { \
    const unsigned short* g_ = B + (size_t)(tn + (h_)*128 + srow) * K + (tt_)*64 + scol; \
    const char* d_ = sB + (((tt_) & 1) * 32768 + (h_)*16384 + w * 1024); \
    gload16(g_, d_); \
    gload16(g_ + (size_t)64 * K, d_ + 8192); \
  } while (0)

  f32x4 acc[8][4] = {};
  bf16x8 af[4][2];
  bf16x8 bf_[2][2][2];

#define LDA(buf_, mh_) do { \
    _Pragma("unroll") for (int m_ = 0; m_ < 4; ++m_) { \
      af[m_][0] = *(const bf16x8*)(sA + (buf_)*32768 + (mh_)*16384 + m_*2048 + aRB + offk0); \
      af[m_][1] = *(const bf16x8*)(sA + (buf_)*32768 + (mh_)*16384 + m_*2048 + aRB + offk1); \
    } \
  } while (0)

#define LDB(buf_, nh_) do { \
    _Pragma("unroll") for (int n_ = 0; n_ < 2; ++n_) { \
      bf_[nh_][n_][0] = *(const bf16x8*)(sB + (buf_)*32768 + (nh_)*16384 + n_*2048 + bRB + offk0); \
      bf_[nh_][n_][1] = *(const bf16x8*)(sB + (buf_)*32768 + (nh_)*16384 + n_*2048 + bRB + offk1); \
    } \
  } while (0)

#define MM(mh_, nh_) do { \
    __builtin_amdgcn_s_setprio(1); \
    _Pragma("unroll") for (int m_ = 0; m_ < 4; ++m_) \
      _Pragma("unroll") for (int n_ = 0; n_ < 2; ++n_) { \
        acc[(mh_)*4 + m_][(nh_)*2 + n_] = \
            mfma16(af[m_][0], bf_[nh_][n_][0], acc[(mh_)*4 + m_][(nh_)*2 + n_]); \
        acc[(mh_)*4 + m_][(nh_)*2 + n_] = \
            mfma16(af[m_][1], bf_[nh_][n_][1], acc[(mh_)*4 + m_][(nh_)*2 + n_]); \
      } \
    __builtin_amdgcn_s_setprio(0); \
  } while (0)

  // ---- prologue: tile0 fully, tile1 first 3 half-tiles; drain tile0 ----
  STAGE_A(0, 0); STAGE_B(0, 0); STAGE_B(0, 1); STAGE_A(0, 1);
  STAGE_A(1, 0); STAGE_B(1, 0); STAGE_B(1, 1);
  WAITVM(6);
  BAR();

  int T = 0;
  for (; T + 3 < NT; T += 2) {
    LDA(0, 0); LDB(0, 0);
    STAGE_A(T + 1, 1);
    BAR(); MM(0, 0); BAR();
    LDB(0, 1);
    STAGE_A(T + 2, 0);
    BAR(); MM(0, 1); BAR();
    LDA(0, 1);
    STAGE_B(T + 2, 0);
    BAR(); MM(1, 0); BAR();
    STAGE_B(T + 2, 1);
    WAITVM(6);
    BAR(); MM(1, 1); BAR();
    LDA(1, 0); LDB(1, 0);
    STAGE_A(T + 2, 1);
    BAR(); MM(0, 0); BAR();
    LDB(1, 1);
    STAGE_A(T + 3, 0);
    BAR(); MM(0, 1); BAR();
    LDA(1, 1);
    STAGE_B(T + 3, 0);
    BAR(); MM(1, 0); BAR();
    STAGE_B(T + 3, 1);
    WAITVM(6);
    BAR(); MM(1, 1); BAR();
  }
  {
    LDA(0, 0); LDB(0, 0);
    STAGE_A(T + 1, 1);
    BAR(); MM(0, 0); BAR();
    LDB(0, 1);
    BAR(); MM(0, 1); BAR();
    LDA(0, 1);
    BAR(); MM(1, 0); BAR();
    WAITVM(0);
    BAR(); MM(1, 1); BAR();
    LDA(1, 0); LDB(1, 0);
    BAR(); MM(0, 0); BAR();
    LDB(1, 1);
    BAR(); MM(0, 1); BAR();
    LDA(1, 1);
    BAR(); MM(1, 0); BAR();
    BAR(); MM(1, 1); BAR();
  }

#pragma unroll
  for (int mh = 0; mh < 2; ++mh)
#pragma unroll
    for (int m = 0; m < 4; ++m)
#pragma unroll
      for (int nh = 0; nh < 2; ++nh)
#pragma unroll
        for (int n = 0; n < 2; ++n)
#pragma unroll
          for (int j = 0; j < 4; ++j) {
            int row = tm + mh * 128 + wr * 64 + m * 16 + q * 4 + j;
            int col = tn + nh * 128 + wc * 32 + n * 16 + lr;
            float v = acc[mh * 4 + m][nh * 2 + n][j];
            if constexpr (sizeof(OutT) == 2)
              C[(size_t)row * N + col] = (OutT)f2b(v);
            else
              C[(size_t)row * N + col] = v;
          }
#undef STAGE_A
#undef STAGE_B
#undef LDA
#undef LDB
#undef MM
}

// ---------------- per-token 16-head attention over head axis ----------------
// R12-proven: swapped QK^T, in-register softmax, shuffle-gathered PV
// A-fragment, distributed all-lane V fetch + shfl_xor(32) reassembly, no LDS.
__global__ __launch_bounds__(256, 4) void attn16(
    const unsigned short* __restrict__ qkv, unsigned short* __restrict__ out) {
  const int t = threadIdx.x, w = t >> 6, l = t & 63;
  const int tok = blockIdx.x * 4 + w;
  const unsigned short* q = qkv + (size_t)tok * 3072;
  const unsigned short* kp = q + 1024;
  const unsigned short* vp = q + 2048;
  const int lr = l & 15, lk = (l >> 4) * 8;

  bf16x8 aq0 = *reinterpret_cast<const bf16x8*>(q + lr * 64 + lk);
  bf16x8 aq1 = *reinterpret_cast<const bf16x8*>(q + lr * 64 + 32 + lk);
  bf16x8 bk0 = *reinterpret_cast<const bf16x8*>(kp + lr * 64 + lk);
  bf16x8 bk1 = *reinterpret_cast<const bf16x8*>(kp + lr * 64 + 32 + lk);

  // distributed V fetch (issue early, consume after softmax)
  const int myLk = ((l >> 4) & 1) * 8;  // shared by l and l^32
  const int jb = (l >> 5) * 4;          // 0 lower half, 4 upper half
  unsigned vlo[4], vhi[4];
#pragma unroll
  for (int b = 0; b < 4; ++b) {
    const unsigned short* vb = vp + (size_t)(myLk + jb) * 64 + b * 16 + lr;
    unsigned short e0 = vb[0];
    unsigned short e1 = vb[64];
    unsigned short e2 = vb[128];
    unsigned short e3 = vb[192];
    vlo[b] = (unsigned)e0 | ((unsigned)e1 << 16);
    vhi[b] = (unsigned)e2 | ((unsigned)e3 << 16);
  }

  f32x4 s = {};
  __builtin_amdgcn_s_setprio(1);
  s = mfma16(bk0, aq0, s);  // swapped: S^T
  s = mfma16(bk1, aq1, s);
  __builtin_amdgcn_s_setprio(0);

  const float cexp = 0.125f * 1.44269504f;
  float mx = fmaxf(fmaxf(s[0], s[1]), fmaxf(s[2], s[3]));
  mx = fmaxf(mx, __shfl_xor(mx, 16));
  mx = fmaxf(mx, __shfl_xor(mx, 32));
  float e0 = exp2f((s[0] - mx) * cexp);
  float e1 = exp2f((s[1] - mx) * cexp);
  float e2 = exp2f((s[2] - mx) * cexp);
  float e3 = exp2f((s[3] - mx) * cexp);
  float sm = (e0 + e1) + (e2 + e3);
  sm += __shfl_xor(sm, 16);
  sm += __shfl_xor(sm, 32);
  float inv = 1.0f / sm;
  float p[4] = {e0 * inv, e1 * inv, e2 * inv, e3 * inv};

  // gather PV A-fragment: av[jj] = P[h=lr][g=(l>>4)*8+jj] for l<32, else 0
  ushort8 au;
#pragma unroll
  for (int jj = 0; jj < 8; ++jj) {
    int src = (lr + (l >> 4) * 32 + (jj >> 2) * 16) & 63;
    float v = __shfl(p[jj & 3], src);
    au[jj] = (l < 32) ? f2b(v) : (unsigned short)0;
  }
  bf16x8 ap = __builtin_bit_cast(bf16x8, au);

  // reassemble V B-fragments: elems 0..3 own rows, 4..7 partner rows
  bf16x8 bv[4];
#pragma unroll
  for (int b = 0; b < 4; ++b) {
    unsigned plo = (unsigned)__shfl_xor((int)vlo[b], 32);
    unsigned phi = (unsigned)__shfl_xor((int)vhi[b], 32);
    uint4v u = {vlo[b], vhi[b], plo, phi};
    bv[b] = __builtin_bit_cast(bf16x8, u);
  }

  f32x4 o[4] = {};
  __builtin_amdgcn_s_setprio(1);
#pragma unroll
  for (int b = 0; b < 4; ++b) o[b] = mfma16(ap, bv[b], o[b]);
  __builtin_amdgcn_s_setprio(0);

  unsigned short* op = out + (size_t)tok * 1024;
#pragma unroll
  for (int b = 0; b < 4; ++b)
#pragma unroll
    for (int j = 0; j < 4; ++j)
      op[((l >> 4) * 4 + j) * 64 + b * 16 + lr] = f2b(o[b][j]);
}

// ---------------------------------------------------------------------------
extern "C" void kernel_launch(void* const* d_in, const int* in_sizes, int n_in,
                              void* d_out, int out_size, void* d_ws, size_t ws_size,
                              hipStream_t stream) {
  const float* x = (const float*)d_in[0];
  const float* Wq = (const float*)d_in[1];
  const float* Wk = (const float*)d_in[2];
  const float* Wv = (const float*)d_in[3];
  const float* Wo = (const float*)d_in[4];

  unsigned short* xb = (unsigned short*)d_ws;            // 64M elems (128 MB)
  unsigned short* wqkv = xb + (size_t)NTOK * E;          // 3M (6 MB)
  unsigned short* wo = wqkv + (size_t)3 * E * E;         // 1M (2 MB)
  unsigned short* qkv = wo + (size_t)E * E;              // 192M (384 MB)
  unsigned short* att = qkv + (size_t)NTOK * 3 * E;      // 64M (128 MB)

  // single convert launch: x (blocks 0..32767) + Wq|Wk|Wv|Wo (32768..34815)
  cvtAll<<<34816, 256, 0, stream>>>(x, Wq, Wk, Wv, Wo, xb, wqkv);

  // QKV: [65536,1024] x [3072,1024]^T -> [65536,3072]
  gemm8<unsigned short><<<(NTOK / 256) * (3 * E / 256), 512, 0, stream>>>(
      xb, wqkv, qkv, NTOK, 3 * E, E, 3 * E / 256);

  attn16<<<NTOK / 4, 256, 0, stream>>>(qkv, att);

  // O-proj: [65536,1024] x [1024,1024]^T -> fp32
  gemm8<float><<<(NTOK / 256) * (E / 256), 512, 0, stream>>>(
      att, wo, (float*)d_out, NTOK, E, E, E / 256);
}